// Round 11
// baseline (51.131 us; speedup 1.0000x reference)
//
#include <hip/hip_runtime.h>
#include <hip/hip_bf16.h>

// B=8, Lq=2048, Lk=2048, D=256. out = softmax(mask? sq_i+sk_j : -1e9) @ V.
// sq cancels in softmax => out[i] = (mask[i]·(e*V)) / (mask[i]·e), e=exp(K·w).
// Kernel 1: eb (bf16) + evB (pre-fragmented MFMA B-operand; coalesced loads).
// Kernel 2: mask-streaming GEMM, BM=64 x BN=256 x BK=64, 512 thr (8 waves,
//   2m x 4n, wave 32r x 64d), grid 256 = 1 block/CU. ROUND-11: mask read
//   EXACTLY ONCE (BN=256 kills the dh duplication that doubled L3 traffic).
//   A staging: 8 thr/row, 32 B contiguous per lane (full-sector txns), rotation
//   swizzle slot=(chunk+row)&7 (verified ~0 conflicts). A: 3-deep LDS ring,
//   2-step reg prefetch. B/e: reg prefetch 1 step ahead from L2-resident evB.
//   Sync: lgkmcnt(0)+s_barrier only — vmcnt never drained. Denominator folded
//   into MFMA (e-column B-frag, wn==0 waves).
// Workspace: evB 8 MB + eb 32 KB.

#define NB 8
#define LQ 2048
#define LK 2048
#define DD 256

typedef __attribute__((ext_vector_type(8))) short short8v;
typedef __attribute__((ext_vector_type(8))) unsigned short ushort8v;
typedef __attribute__((ext_vector_type(4))) float f32x4;

__device__ inline unsigned short f2bf(float x) {
  union { __hip_bfloat16 h; unsigned short u; } cv;
  cv.h = __float2bfloat16(x);
  return cv.u;
}

__device__ inline uint2 pack_mask4(const int4 a) {
  uint2 p;
  p.x = (a.x ? 0x3F80u : 0u) | (a.y ? 0x3F800000u : 0u);
  p.y = (a.z ? 0x3F80u : 0u) | (a.w ? 0x3F800000u : 0u);
  return p;
}

// ---------------- Kernel 1: eb = bf16(exp(K·w)); evB = pre-fragmented e*V -----
// grid 8*64=512 (b = blk&7 -> XCD), 256 thr. Block owns batch b, 32 j-rows (ks).
__global__ __launch_bounds__(256) void bah_precompute(
    const float* __restrict__ key, const float* __restrict__ value,
    const float* __restrict__ w, unsigned short* __restrict__ evB,
    unsigned short* __restrict__ eb)
{
  __shared__ float e_s[32];
  __shared__ unsigned short t_s[32][260];   // padded: conflict-free transpose

  const int t = threadIdx.x;
  const int lane = t & 63;
  const int wid = t >> 6;                   // 0..3
  const int blk = blockIdx.x;
  const int b = blk & 7;
  const int ks = blk >> 3;                  // 0..63 (32-k slice)
  const int j0 = ks * 32;

  const float4 wv4 = reinterpret_cast<const float4*>(w)[lane];

#pragma unroll
  for (int r8 = 0; r8 < 8; ++r8) {
    const int r = wid * 8 + r8;
    const size_t row = (size_t)b * LK + j0 + r;
    const float4 kv = reinterpret_cast<const float4*>(key + row * DD)[lane];
    float s = kv.x * wv4.x + kv.y * wv4.y + kv.z * wv4.z + kv.w * wv4.w;
#pragma unroll
    for (int off = 32; off; off >>= 1) s += __shfl_xor(s, off);
    const float e = __expf(s);              // |K·w| small: no max-shift needed
    if (lane == 0) { e_s[r] = e; eb[row] = f2bf(e); }
  }
  __syncthreads();

#pragma unroll
  for (int g = 0; g < 8; ++g) {
    const int jr = g * 4 + wid;
    const size_t row = (size_t)b * LK + j0 + jr;
    const float4 vv = reinterpret_cast<const float4*>(value + row * DD)[lane];
    const float e = e_s[jr];
    ushort4 u;
    u.x = f2bf(e * vv.x);
    u.y = f2bf(e * vv.y);
    u.z = f2bf(e * vv.z);
    u.w = f2bf(e * vv.w);
    *reinterpret_cast<ushort4*>(&t_s[jr][lane * 4]) = u;
  }
  __syncthreads();

  // frag gather: lane holds B[k=8*(lane>>4)+i][d=n*16+(lane&15)]
  const int lr = lane & 15;
  const int lj = lane >> 4;
#pragma unroll
  for (int n4 = 0; n4 < 4; ++n4) {
    const int n = wid * 4 + n4;
    ushort8v va;
#pragma unroll
    for (int i = 0; i < 8; ++i) va[i] = t_s[lj * 8 + i][n * 16 + lr];
    *reinterpret_cast<ushort8v*>(
        evB + ((size_t)((b * 64 + ks) * 16 + n) * 64 + lane) * 8) = va;
  }
}

// ---------------- Kernel 2: mask-streaming masked GEMM ------------------------
// grid 256 (1 block/CU): blk = b + 8*itile. 512 thr = 8 waves (2m x 4n).
// Block tile: 64 rows x 256 d; wave (wm,wn): rows [wm*32,+32), d [wn*64,+64).
__global__ __launch_bounds__(512, 1) void bah_gemm(
    const int* __restrict__ mask, const unsigned short* __restrict__ evB,
    const unsigned short* __restrict__ eb, float* __restrict__ out)
{
  __shared__ unsigned short A_s[3][64 * 64];   // 3-deep ring, 24 KB, rot-swizzled
  __shared__ float denom_s[64];

  const int t = threadIdx.x;
  const int lane = t & 63;
  const int wid = t >> 6;                   // 0..7
  const int wm = wid >> 2;                  // 0..1: 32-row half
  const int wn = wid & 3;                   // 0..3: 64-d quarter
  const int lr = lane & 15;
  const int lj = lane >> 4;

  const int blk = blockIdx.x;
  const int b = blk & 7;                    // batch -> XCD (evB L2-resident)
  const int i0 = (blk >> 3) * 64;

  // ---- A staging: 8 thr/row, each lane 16 B contiguous; 2 loads/step (j=0,1)
  //      cover 64 ints/row. Per wave instr: 8 rows x 128 B full sectors. ----
  const int sr = t >> 3;                    // 0..63
  const int q = t & 7;
  const int* aptr = mask + ((size_t)b * LQ + i0 + sr) * LK + q * 4;
  // LDS slots: k-int kk = q*4 + j*32 -> chunk c2 = (q>>1) + j*4, half (q&1).
  // Rotation swizzle: slot = (c2 + sr) & 7.
  int awr[2];
#pragma unroll
  for (int j = 0; j < 2; ++j)
    awr[j] = sr * 64 + ((((q >> 1) + j * 4 + sr) & 7) * 8) + (q & 1) * 4;

  // B frag pointers (pre-fragged evB): stride 8192 ushorts per 32-k slice
  const unsigned short* bB[4];
#pragma unroll
  for (int nn = 0; nn < 4; ++nn)
    bB[nn] = evB + ((size_t)(b * 64) * 16 + wn * 4 + nn) * 512 + lane * 8;
  const unsigned short* ebb = eb + b * LK + lj * 8;

  // A frag read offsets: row = wm*32 + m*16 + lr; chunk (h*4+lj) rotated by row
  int afo[2][2];
#pragma unroll
  for (int m = 0; m < 2; ++m) {
    const int row = wm * 32 + m * 16 + lr;
#pragma unroll
    for (int h = 0; h < 2; ++h)
      afo[m][h] = row * 64 + (((h * 4 + lj + row) & 7) * 8);
  }

  f32x4 acc[2][4] = {};
  f32x4 accd[2] = {};
  const short8v z8 = {};

  short8v bfr[2][2][4];                     // [buf][h][nn] — 1 step ahead
  short8v efr[2][2] = {{z8, z8}, {z8, z8}};

  // ---- prologue: A(0)->ring0; A(1)->regs; B(0)/e(0)->reg buf0 ----
#pragma unroll
  for (int j = 0; j < 2; ++j) {
    const int4 p = *reinterpret_cast<const int4*>(aptr + j * 32);
    *reinterpret_cast<uint2*>(&A_s[0][awr[j]]) = pack_mask4(p);
  }
  int4 aC0 = *reinterpret_cast<const int4*>(aptr + 64);
  int4 aC1 = *reinterpret_cast<const int4*>(aptr + 64 + 32);
#pragma unroll
  for (int h = 0; h < 2; ++h) {
#pragma unroll
    for (int nn = 0; nn < 4; ++nn)
      bfr[0][h][nn] = *reinterpret_cast<const short8v*>(bB[nn] + (size_t)h * 8192);
    if (wn == 0 && lr == 0)
      efr[0][h] = *reinterpret_cast<const short8v*>(ebb + h * 32);
  }
  __syncthreads();

#pragma unroll 2
  for (int tt = 0; tt < 32; ++tt) {
    const int cur = tt & 1;
    const int nxt = cur ^ 1;
    const int bufC = tt % 3;
    const int bufW = (tt + 1) % 3;

    // ---- issue: A(t+2), B(t+1), e(t+1) (cross barrier via counted vmcnt) ----
    const int k2 = ((tt + 2) & 31) * 64;    // wrap: dead loads, harmless
    const int4 aN0 = *reinterpret_cast<const int4*>(aptr + k2);
    const int4 aN1 = *reinterpret_cast<const int4*>(aptr + k2 + 32);
    const int kn = ((tt + 1) & 31) * 2;
#pragma unroll
    for (int h = 0; h < 2; ++h) {
#pragma unroll
      for (int nn = 0; nn < 4; ++nn)
        bfr[nxt][h][nn] = *reinterpret_cast<const short8v*>(
            bB[nn] + (size_t)(kn + h) * 8192);
      short8v ev = z8;
      if (wn == 0 && lr == 0)
        ev = *reinterpret_cast<const short8v*>(ebb + (kn + h) * 32);
      efr[nxt][h] = ev;
    }
    __builtin_amdgcn_sched_barrier(0);

    // ---- write A(t+1) from regs; certify with lgkm + barrier only ----
    *reinterpret_cast<uint2*>(&A_s[bufW][awr[0]]) = pack_mask4(aC0);
    *reinterpret_cast<uint2*>(&A_s[bufW][awr[1]]) = pack_mask4(aC1);
    asm volatile("s_waitcnt lgkmcnt(0)" ::: "memory");
    __builtin_amdgcn_sched_barrier(0);
    __builtin_amdgcn_s_barrier();
    __builtin_amdgcn_sched_barrier(0);

    // ---- compute tile t from LDS-A + reg-B ----
#pragma unroll
    for (int h = 0; h < 2; ++h) {
      short8v af[2];
#pragma unroll
      for (int m = 0; m < 2; ++m)
        af[m] = *reinterpret_cast<const short8v*>(&A_s[bufC][afo[m][h]]);
      __builtin_amdgcn_s_setprio(1);
      if (wn == 0) {
#pragma unroll
        for (int m = 0; m < 2; ++m)
          accd[m] = __builtin_amdgcn_mfma_f32_16x16x32_bf16(
              af[m], efr[cur][h], accd[m], 0, 0, 0);
      }
#pragma unroll
      for (int m = 0; m < 2; ++m)
#pragma unroll
        for (int nn = 0; nn < 4; ++nn)
          acc[m][nn] = __builtin_amdgcn_mfma_f32_16x16x32_bf16(
              af[m], bfr[cur][h][nn], acc[m][nn], 0, 0, 0);
      __builtin_amdgcn_s_setprio(0);
    }
    aC0 = aN0; aC1 = aN1;
  }

  // ---- denominator broadcast (C col 0 lives in lanes with lr==0) ----
  if (wn == 0 && lr == 0) {
#pragma unroll
    for (int m = 0; m < 2; ++m)
#pragma unroll
      for (int qq = 0; qq < 4; ++qq)
        denom_s[wm * 32 + m * 16 + lj * 4 + qq] = accd[m][qq];
  }
  __syncthreads();

  // ---- epilogue: divide and store (C layout: col=lane&15, row=lj*4+q) ----
#pragma unroll
  for (int m = 0; m < 2; ++m) {
    const int row0 = wm * 32 + m * 16 + lj * 4;
    float inv[4];
#pragma unroll
    for (int qq = 0; qq < 4; ++qq) {
      const float dn = denom_s[row0 + qq];
      inv[qq] = (dn != 0.f) ? 1.f / dn : 0.f;   // all-masked row: avoid NaN
    }
#pragma unroll
    for (int nn = 0; nn < 4; ++nn) {
      const int col = wn * 64 + nn * 16 + lr;
#pragma unroll
      for (int qq = 0; qq < 4; ++qq)
        out[((size_t)b * LQ + (i0 + row0 + qq)) * DD + col] = acc[m][nn][qq] * inv[qq];
    }
  }
}

extern "C" void kernel_launch(void* const* d_in, const int* in_sizes, int n_in,
                              void* d_out, int out_size, void* d_ws, size_t ws_size,
                              hipStream_t stream) {
  // inputs: 0=query (unused: softmax shift-invariance), 1=key, 2=value, 3=mask, 4=w_align
  const float* key   = (const float*)d_in[1];
  const float* value = (const float*)d_in[2];
  const int*   mask  = (const int*)d_in[3];
  const float* w     = (const float*)d_in[4];
  float* out = (float*)d_out;

  unsigned short* evB = (unsigned short*)d_ws;                              // 8 MB
  unsigned short* eb  = (unsigned short*)((char*)d_ws + (size_t)NB * DD * LK * 2);

  bah_precompute<<<NB * (LK / 32), 256, 0, stream>>>(key, value, w, evB, eb);
  bah_gemm<<<256, 512, 0, stream>>>(mask, evB, eb, out);
}